// Round 1
// baseline (514.945 us; speedup 1.0000x reference)
//
#include <hip/hip_runtime.h>

typedef short s8v __attribute__((ext_vector_type(8)));
typedef float f4 __attribute__((ext_vector_type(4)));

__device__ inline float bf2f(unsigned short u) {
  union { unsigned i; float f; } x; x.i = (unsigned)u << 16; return x.f;
}
__device__ inline unsigned short f2bf(float f) {
  union { float f; unsigned i; } x; x.f = f;
  return (unsigned short)((x.i + 0x7fffu + ((x.i >> 16) & 1u)) >> 16);
}

__device__ inline void gload16(const void* g, void* l) {
  __builtin_amdgcn_global_load_lds(
      (const __attribute__((address_space(1))) unsigned int*)g,
      (__attribute__((address_space(3))) unsigned int*)l, 16, 0, 0);
}

// ---------------- copy x -> out ----------------
__global__ __launch_bounds__(256) void copy4(const float4* __restrict__ src,
                                             float4* __restrict__ dst, int n4) {
  int i = blockIdx.x * blockDim.x + threadIdx.x;
  int stride = gridDim.x * blockDim.x;
  for (; i < n4; i += stride) dst[i] = src[i];
}

// ---------------- layernorm of rep rows -> bf16 h ----------------
__global__ __launch_bounds__(256) void ln_kernel(const float* __restrict__ x,
                                                 const float* __restrict__ g,
                                                 const float* __restrict__ bvec,
                                                 unsigned short* __restrict__ h) {
  int m = blockIdx.x;                 // 0..4095 = b*N + n
  int b = m >> 11, n = m & 2047;
  int s = n >> 4, rl = n & 15;
  const float* row = x + ((size_t)((b * 128 + s) * 128 + rl)) * 768;
  int t = threadIdx.x;
  float v0 = row[t], v1 = row[t + 256], v2 = row[t + 512];
  float sum = v0 + v1 + v2;
  float sq = v0 * v0 + v1 * v1 + v2 * v2;
  __shared__ float rs[4], rq[4];
#pragma unroll
  for (int o = 32; o; o >>= 1) {
    sum += __shfl_down(sum, o);
    sq += __shfl_down(sq, o);
  }
  if ((t & 63) == 0) { rs[t >> 6] = sum; rq[t >> 6] = sq; }
  __syncthreads();
  sum = rs[0] + rs[1] + rs[2] + rs[3];
  sq = rq[0] + rq[1] + rq[2] + rq[3];
  float mu = sum * (1.f / 768.f);
  float var = sq * (1.f / 768.f) - mu * mu;
  float inv = rsqrtf(var + 1e-5f);
  unsigned short* hrow = h + (size_t)m * 768;
  hrow[t] = f2bf((v0 - mu) * inv * g[t] + bvec[t]);
  hrow[t + 256] = f2bf((v1 - mu) * inv * g[t + 256] + bvec[t + 256]);
  hrow[t + 512] = f2bf((v2 - mu) * inv * g[t + 512] + bvec[t + 512]);
}

// ---------------- weight transpose + bf16 convert ----------------
// dst[n][k] = src[k][n]; K=768 fixed.
__global__ __launch_bounds__(256) void transp_cvt(const float* __restrict__ Wq,
                                                  const float* __restrict__ Wk,
                                                  const float* __restrict__ Wv,
                                                  const float* __restrict__ Wo,
                                                  unsigned short* __restrict__ Bt,
                                                  unsigned short* __restrict__ Bto) {
  int z = blockIdx.z;
  const float* src; unsigned short* dst; int N;
  if (z == 0) { src = Wq; dst = Bt; N = 512; }
  else if (z == 1) { src = Wk; dst = Bt + (size_t)512 * 768; N = 512; }
  else if (z == 2) { src = Wv; dst = Bt + (size_t)1024 * 768; N = 768; }
  else { src = Wo; dst = Bto; N = 768; }
  int n0 = blockIdx.x << 6, k0 = blockIdx.y << 6;
  if (n0 >= N) return;
  __shared__ float tile[64][65];
  int t = threadIdx.x;
  int c4 = (t & 15) << 2, rr = t >> 4;
#pragma unroll
  for (int i = 0; i < 4; ++i) {
    int kr = rr + (i << 4);
    float4 v = *(const float4*)(src + (size_t)(k0 + kr) * N + n0 + c4);
    tile[c4 + 0][kr] = v.x; tile[c4 + 1][kr] = v.y;
    tile[c4 + 2][kr] = v.z; tile[c4 + 3][kr] = v.w;
  }
  __syncthreads();
  int rowN = t >> 2, kc = (t & 3) << 4;
#pragma unroll
  for (int j = 0; j < 16; ++j)
    dst[(size_t)(n0 + rowN) * 768 + k0 + kc + j] = f2bf(tile[rowN][kc + j]);
}

// ---------------- rel_k GEMM (small, fp32 in, bf16 out) ----------------
// C = A(M x K) @ B(K x N), M=4095, N=512, K=96
__global__ __launch_bounds__(256) void gemm_rel(const float* __restrict__ A,
                                                const float* __restrict__ Bw,
                                                unsigned short* __restrict__ C0,
                                                int M, int Nn, int K) {
  __shared__ float As[16][68];
  __shared__ float Bs[16][68];
  int t = threadIdx.x;
  int tx = t & 15, ty = t >> 4;
  int row0 = blockIdx.y << 6, col0 = blockIdx.x << 6;
  float acc[4][4] = {{0.f}};
  int ar = t >> 2, ac = (t & 3) << 2;
  int br = t >> 4, bc = (t & 15) << 2;
  for (int k0 = 0; k0 < K; k0 += 16) {
    float4 av = make_float4(0.f, 0.f, 0.f, 0.f);
    if (row0 + ar < M) av = *(const float4*)(A + (size_t)(row0 + ar) * K + k0 + ac);
    As[ac + 0][ar] = av.x; As[ac + 1][ar] = av.y;
    As[ac + 2][ar] = av.z; As[ac + 3][ar] = av.w;
    float4 bv = *(const float4*)(Bw + (size_t)(k0 + br) * Nn + col0 + bc);
    *(float4*)&Bs[br][bc] = bv;
    __syncthreads();
#pragma unroll
    for (int kk = 0; kk < 16; ++kk) {
      float4 a = *(const float4*)&As[kk][ty << 2];
      float4 b = *(const float4*)&Bs[kk][tx << 2];
      float arr[4] = {a.x, a.y, a.z, a.w};
      float brr[4] = {b.x, b.y, b.z, b.w};
#pragma unroll
      for (int i = 0; i < 4; ++i)
#pragma unroll
        for (int j = 0; j < 4; ++j) acc[i][j] += arr[i] * brr[j];
    }
    __syncthreads();
  }
#pragma unroll
  for (int i = 0; i < 4; ++i) {
    int r = row0 + (ty << 2) + i;
    if (r >= M) continue;
    int colb = col0 + (tx << 2);
    unsigned pk0 = f2bf(acc[i][0]) | ((unsigned)f2bf(acc[i][1]) << 16);
    unsigned pk1 = f2bf(acc[i][2]) | ((unsigned)f2bf(acc[i][3]) << 16);
    *(uint2*)(C0 + (size_t)r * Nn + colb) = make_uint2(pk0, pk1);
  }
}

// ---------------- MFMA GEMM (m97 structure): C = A(Mx768) @ Bt^T ----------------
// A bf16 row-major (K=768 contiguous), Bt bf16 N x 768 row-major.
// MODE 0: fused QKV epilogue (N=1792: q|k|v). MODE 1: out epilogue (N=768).
template <int MODE>
__global__ __launch_bounds__(256) void gemm_mfma(
    const unsigned short* __restrict__ A, const unsigned short* __restrict__ Bt,
    unsigned short* __restrict__ qw, unsigned short* __restrict__ qr,
    unsigned short* __restrict__ kbuf, unsigned short* __restrict__ vt,
    const float* __restrict__ rwb, const float* __restrict__ rrb,
    const float* __restrict__ x, const float* __restrict__ bo,
    float* __restrict__ out) {
  __shared__ __align__(16) short As[128 * 64];
  __shared__ __align__(16) short Bs[128 * 64];
  const int t = threadIdx.x;
  const int w = t >> 6, lane = t & 63;
  const int m16 = lane & 15, quad = lane >> 4;
  const int wm = w >> 1, wn = w & 1;
  const int m0 = blockIdx.y << 7, n0 = blockIdx.x << 7;
  const int K = 768;

  f4 acc[4][4];
#pragma unroll
  for (int i = 0; i < 4; ++i)
#pragma unroll
    for (int j = 0; j < 4; ++j) acc[i][j] = (f4){0.f, 0.f, 0.f, 0.f};

  const int rA = lane >> 3;   // row-within-segment
  const int cA = lane & 7;    // chunk slot

  for (int k0 = 0; k0 < K; k0 += 64) {
    __syncthreads();
#pragma unroll
    for (int i = 0; i < 4; ++i) {
      int seg = (w << 2) + i;            // 16 segments of 64 slots
      int r = (seg << 3) + rA;           // tile row 0..127
      int cg = cA ^ (r & 7);             // global chunk for this slot
      gload16(A + (size_t)(m0 + r) * K + k0 + (cg << 3), (short*)As + (seg << 9));
      gload16(Bt + (size_t)(n0 + r) * K + k0 + (cg << 3), (short*)Bs + (seg << 9));
    }
    __syncthreads();
#pragma unroll
    for (int kb = 0; kb < 2; ++kb) {
      int cs = ((kb << 2) + quad) ^ (m16 & 7);
      s8v af[4], bf[4];
#pragma unroll
      for (int mt = 0; mt < 4; ++mt) {
        int r = (wm << 6) + (mt << 4) + m16;
        af[mt] = *(const s8v*)(As + (r << 6) + (cs << 3));
      }
#pragma unroll
      for (int nt = 0; nt < 4; ++nt) {
        int rn = (wn << 6) + (nt << 4) + m16;
        bf[nt] = *(const s8v*)(Bs + (rn << 6) + (cs << 3));
      }
#pragma unroll
      for (int mt = 0; mt < 4; ++mt)
#pragma unroll
        for (int nt = 0; nt < 4; ++nt)
          acc[mt][nt] = __builtin_amdgcn_mfma_f32_16x16x32_bf16(af[mt], bf[nt], acc[mt][nt], 0, 0, 0);
    }
  }

#pragma unroll
  for (int nt = 0; nt < 4; ++nt) {
    int n = n0 + (wn << 6) + (nt << 4) + m16;
#pragma unroll
    for (int mt = 0; mt < 4; ++mt) {
#pragma unroll
      for (int rr = 0; rr < 4; ++rr) {
        int m = m0 + (wm << 6) + (mt << 4) + (quad << 2) + rr;
        float v = acc[mt][nt][rr];
        if (MODE == 0) {
          if (n < 512) {
            float vs = v * 0.125f;
            qw[(size_t)m * 512 + n] = f2bf(vs + rwb[n]);
            qr[(size_t)m * 512 + n] = f2bf(vs + rrb[n]);
          } else if (n < 1024) {
            kbuf[(size_t)m * 512 + (n - 512)] = f2bf(v);
          } else {
            int col = n - 1024;
            int b = m >> 11, j = m & 2047;
            vt[(((size_t)(b * 768 + col)) << 11) + j] = f2bf(v);
          }
        } else {
          int b = m >> 11, nn2 = m & 2047;
          int s = nn2 >> 4, rl = nn2 & 15;
          size_t base = ((size_t)((b * 128 + s) * 128 + rl)) * 768;
          out[base + n] = x[base + n] + v + bo[n];
        }
      }
    }
  }
}

// ---------------- MFMA flash attention: direct-global fragments, 2 barriers/iter ----------------
__global__ __launch_bounds__(256) void attn_kernel(
    const unsigned short* __restrict__ qw_g, const unsigned short* __restrict__ qr_g,
    const unsigned short* __restrict__ k_g, const unsigned short* __restrict__ vt_g,
    const unsigned short* __restrict__ rk_g, unsigned short* __restrict__ ao) {
  const int qt = blockIdx.x, hh = blockIdx.y, b = blockIdx.z;
  const int i0 = qt << 5;
  const int t = threadIdx.x;
  const int lane = t & 63, w = t >> 6;
  const int m16 = lane & 15, quad = lane >> 4;
  const int mi = w & 1, njb = w >> 1;
  const int sr = t >> 3, sg = t & 7;

  __shared__ __align__(16) short qw_s[32 * 64];
  __shared__ __align__(16) short qr_s[32 * 64];
  __shared__ __align__(16) short pb_s[32 * 64];
  __shared__ float p_s[32][68];
  __shared__ short t_s[32][104];
  __shared__ float alpha_s[32];
  __shared__ float linv_s[32];

  // stage Q (content / rel) tiles once, XOR-swizzled for conflict-free ds_read_b128
  for (int u = t; u < 512; u += 256) {
    int tile = u >> 8, idx = u & 255, r = idx >> 3, ch = idx & 7;
    const unsigned short* src =
        (tile ? qr_g : qw_g) + (((size_t)(b * 2048 + i0 + r)) << 9) + (hh << 6) + (ch << 3);
    int4 vdat = *(const int4*)src;
    short* dst = (tile ? qr_s : qw_s) + r * 64 + (((ch ^ (r & 7))) << 3);
    *(int4*)dst = vdat;
  }
  __syncthreads();

  float m_i = -1e30f, l_i = 0.f;
  f4 o0 = {0.f, 0.f, 0.f, 0.f}, o1 = o0, o2 = o0;
  const int arow = mi * 16 + m16;
  const int asw = arow & 7;
  const int crow = mi * 16 + quad * 4;
  const int brow0 = njb * 16 + m16;

  // per-lane global fragment base pointers (fragments are 16B contiguous rows)
  const unsigned short* kbase = k_g + (((size_t)(b * 2048 + brow0)) << 9) + (hh << 6);
  const unsigned short* vbase = vt_g + (((size_t)(b * 768 + hh * 96 + brow0)) << 11);

  for (int j0 = 0; j0 < 2048; j0 += 64) {
    const int rbase = 2047 + j0 - i0 - 31;
    int r2row = rbase + brow0 + 64;          // rel rows 64..95; clamp row 4095 (never read)
    if (r2row > 4094) r2row = 4094;
    const unsigned short* kk = kbase + ((size_t)j0 << 9);
    const unsigned short* rb0 = rk_g + (((size_t)(rbase + brow0)) << 9) + (hh << 6);
    const unsigned short* rb1 = rk_g + (((size_t)(rbase + brow0 + 32)) << 9) + (hh << 6);
    const unsigned short* rb2 = rk_g + (((size_t)r2row) << 9) + (hh << 6);

    f4 c0 = {0.f, 0.f, 0.f, 0.f}, c1 = c0;
    f4 r0 = c0, r1 = c0, r2 = c0;
#pragma unroll
    for (int kb = 0; kb < 2; ++kb) {
      const int cidx = (kb << 2) + quad;
      const int co = (cidx ^ asw) << 3;
      s8v aq = *(const s8v*)(qw_s + arow * 64 + co);
      s8v ar = *(const s8v*)(qr_s + arow * 64 + co);
      s8v bk0 = *(const s8v*)(kk + (cidx << 3));
      s8v bk1 = *(const s8v*)(kk + ((size_t)32 << 9) + (cidx << 3));
      s8v br0 = *(const s8v*)(rb0 + (cidx << 3));
      s8v br1 = *(const s8v*)(rb1 + (cidx << 3));
      s8v br2 = *(const s8v*)(rb2 + (cidx << 3));
      __builtin_amdgcn_s_setprio(1);
      c0 = __builtin_amdgcn_mfma_f32_16x16x32_bf16(aq, bk0, c0, 0, 0, 0);
      c1 = __builtin_amdgcn_mfma_f32_16x16x32_bf16(aq, bk1, c1, 0, 0, 0);
      r0 = __builtin_amdgcn_mfma_f32_16x16x32_bf16(ar, br0, r0, 0, 0, 0);
      r1 = __builtin_amdgcn_mfma_f32_16x16x32_bf16(ar, br1, r1, 0, 0, 0);
      r2 = __builtin_amdgcn_mfma_f32_16x16x32_bf16(ar, br2, r2, 0, 0, 0);
      __builtin_amdgcn_s_setprio(0);
    }
#pragma unroll
    for (int rr = 0; rr < 4; ++rr) {
      p_s[crow + rr][njb * 16 + m16] = c0[rr];
      p_s[crow + rr][(njb + 2) * 16 + m16] = c1[rr];
      t_s[crow + rr][njb * 16 + m16] = (short)f2bf(r0[rr]);
      t_s[crow + rr][(njb + 2) * 16 + m16] = (short)f2bf(r1[rr]);
      t_s[crow + rr][(njb + 4) * 16 + m16] = (short)f2bf(r2[rr]);
    }
    __syncthreads();

    float sv[8];
    float mx = -1e30f;
#pragma unroll
    for (int j2 = 0; j2 < 8; ++j2) {
      int c = sg + (j2 << 3);
      float s = p_s[sr][c] + bf2f((unsigned short)t_s[sr][c - sr + 31]);
      sv[j2] = s;
      mx = fmaxf(mx, s);
    }
    mx = fmaxf(mx, __shfl_xor(mx, 1));
    mx = fmaxf(mx, __shfl_xor(mx, 2));
    mx = fmaxf(mx, __shfl_xor(mx, 4));
    float m_new = fmaxf(m_i, mx);
    float al = __expf(m_i - m_new);
    float sm = 0.f;
#pragma unroll
    for (int j2 = 0; j2 < 8; ++j2) {
      float p = __expf(sv[j2] - m_new);
      sm += p;
      pb_s[sr * 64 + ((j2 ^ (sr & 7)) << 3) + sg] = (short)f2bf(p);
    }
    sm += __shfl_xor(sm, 1);
    sm += __shfl_xor(sm, 2);
    sm += __shfl_xor(sm, 4);
    l_i = l_i * al + sm;
    m_i = m_new;
    if (sg == 0) alpha_s[sr] = al;
    __syncthreads();

#pragma unroll
    for (int rr = 0; rr < 4; ++rr) {
      float a = alpha_s[crow + rr];
      o0[rr] *= a; o1[rr] *= a; o2[rr] *= a;
    }
    const unsigned short* vb = vbase + j0;
#pragma unroll
    for (int kb = 0; kb < 2; ++kb) {
      const int cidx = (kb << 2) + quad;
      const int co = (cidx ^ asw) << 3;
      s8v ap = *(const s8v*)(pb_s + arow * 64 + co);
      s8v b0v = *(const s8v*)(vb + (cidx << 3));
      s8v b1v = *(const s8v*)(vb + ((size_t)32 << 11) + (cidx << 3));
      s8v b2v = *(const s8v*)(vb + ((size_t)64 << 11) + (cidx << 3));
      __builtin_amdgcn_s_setprio(1);
      o0 = __builtin_amdgcn_mfma_f32_16x16x32_bf16(ap, b0v, o0, 0, 0, 0);
      o1 = __builtin_amdgcn_mfma_f32_16x16x32_bf16(ap, b1v, o1, 0, 0, 0);
      o2 = __builtin_amdgcn_mfma_f32_16x16x32_bf16(ap, b2v, o2, 0, 0, 0);
      __builtin_amdgcn_s_setprio(0);
    }
  }

  if (sg == 0) linv_s[sr] = 1.f / l_i;
  __syncthreads();
#pragma unroll
  for (int rr = 0; rr < 4; ++rr) {
    int row = crow + rr;
    float inv = linv_s[row];
    size_t gbase = ((size_t)(b * 2048 + i0 + row)) * 768 + hh * 96;
    ao[gbase + njb * 16 + m16] = f2bf(o0[rr] * inv);
    ao[gbase + (njb + 2) * 16 + m16] = f2bf(o1[rr] * inv);
    ao[gbase + (njb + 4) * 16 + m16] = f2bf(o2[rr] * inv);
  }
}

// ---------------- launch ----------------
extern "C" void kernel_launch(void* const* d_in, const int* in_sizes, int n_in,
                              void* d_out, int out_size, void* d_ws, size_t ws_size,
                              hipStream_t stream) {
  (void)in_sizes; (void)n_in; (void)out_size; (void)ws_size;
  const float* x = (const float*)d_in[0];
  const float* ln_g = (const float*)d_in[1];
  const float* ln_b = (const float*)d_in[2];
  const float* Wq = (const float*)d_in[3];
  const float* Wk = (const float*)d_in[4];
  const float* Wv = (const float*)d_in[5];
  const float* Wr = (const float*)d_in[6];
  const float* rwb = (const float*)d_in[7];
  const float* rrb = (const float*)d_in[8];
  const float* Wo = (const float*)d_in[9];
  const float* bo = (const float*)d_in[10];
  const float* pe = (const float*)d_in[11];
  float* out = (float*)d_out;

  char* p = (char*)d_ws;
  unsigned short* hbf = (unsigned short*)p; p += (size_t)4096 * 768 * 2;
  unsigned short* qw = (unsigned short*)p;  p += (size_t)4096 * 512 * 2;
  unsigned short* qr = (unsigned short*)p;  p += (size_t)4096 * 512 * 2;
  unsigned short* kb = (unsigned short*)p;  p += (size_t)4096 * 512 * 2;
  unsigned short* vt = (unsigned short*)p;  p += (size_t)4096 * 768 * 2;
  unsigned short* rk = (unsigned short*)p;  p += (size_t)4095 * 512 * 2;
  unsigned short* ao = (unsigned short*)p;  p += (size_t)4096 * 768 * 2;
  unsigned short* Bt = (unsigned short*)p;  p += (size_t)1792 * 768 * 2;
  unsigned short* Bto = (unsigned short*)p;

  transp_cvt<<<dim3(12, 12, 4), dim3(256), 0, stream>>>(Wq, Wk, Wv, Wo, Bt, Bto);
  copy4<<<dim3(2048), dim3(256), 0, stream>>>((const float4*)x, (float4*)out, 6291456);
  ln_kernel<<<dim3(4096), dim3(256), 0, stream>>>(x, ln_g, ln_b, hbf);
  gemm_rel<<<dim3(8, 64), dim3(256), 0, stream>>>(pe, Wr, rk, 4095, 512, 96);
  gemm_mfma<0><<<dim3(14, 32), dim3(256), 0, stream>>>(hbf, Bt, qw, qr, kb, vt, rwb, rrb,
                                                       nullptr, nullptr, nullptr);
  attn_kernel<<<dim3(64, 8, 2), dim3(256), 0, stream>>>(qw, qr, kb, vt, rk, ao);
  gemm_mfma<1><<<dim3(6, 32), dim3(256), 0, stream>>>(ao, Bto, nullptr, nullptr, nullptr,
                                                      nullptr, nullptr, nullptr, x, bo, out);
}

// Round 2
// 405.087 us; speedup vs baseline: 1.2712x; 1.2712x over previous
//
#include <hip/hip_runtime.h>

typedef short s8v __attribute__((ext_vector_type(8)));
typedef float f4 __attribute__((ext_vector_type(4)));

__device__ inline float bf2f(unsigned short u) {
  union { unsigned i; float f; } x; x.i = (unsigned)u << 16; return x.f;
}
__device__ inline unsigned short f2bf(float f) {
  union { float f; unsigned i; } x; x.f = f;
  return (unsigned short)((x.i + 0x7fffu + ((x.i >> 16) & 1u)) >> 16);
}

__device__ inline void gload16(const void* g, void* l) {
  __builtin_amdgcn_global_load_lds(
      (const __attribute__((address_space(1))) unsigned int*)g,
      (__attribute__((address_space(3))) unsigned int*)l, 16, 0, 0);
}

// ---------------- copy x -> out ----------------
__global__ __launch_bounds__(256) void copy4(const float4* __restrict__ src,
                                             float4* __restrict__ dst, int n4) {
  int i = blockIdx.x * blockDim.x + threadIdx.x;
  int stride = gridDim.x * blockDim.x;
  for (; i < n4; i += stride) dst[i] = src[i];
}

// ---------------- layernorm of rep rows -> bf16 h ----------------
__global__ __launch_bounds__(256) void ln_kernel(const float* __restrict__ x,
                                                 const float* __restrict__ g,
                                                 const float* __restrict__ bvec,
                                                 unsigned short* __restrict__ h) {
  int m = blockIdx.x;                 // 0..4095 = b*N + n
  int b = m >> 11, n = m & 2047;
  int s = n >> 4, rl = n & 15;
  const float* row = x + ((size_t)((b * 128 + s) * 128 + rl)) * 768;
  int t = threadIdx.x;
  float v0 = row[t], v1 = row[t + 256], v2 = row[t + 512];
  float sum = v0 + v1 + v2;
  float sq = v0 * v0 + v1 * v1 + v2 * v2;
  __shared__ float rs[4], rq[4];
#pragma unroll
  for (int o = 32; o; o >>= 1) {
    sum += __shfl_down(sum, o);
    sq += __shfl_down(sq, o);
  }
  if ((t & 63) == 0) { rs[t >> 6] = sum; rq[t >> 6] = sq; }
  __syncthreads();
  sum = rs[0] + rs[1] + rs[2] + rs[3];
  sq = rq[0] + rq[1] + rq[2] + rq[3];
  float mu = sum * (1.f / 768.f);
  float var = sq * (1.f / 768.f) - mu * mu;
  float inv = rsqrtf(var + 1e-5f);
  unsigned short* hrow = h + (size_t)m * 768;
  hrow[t] = f2bf((v0 - mu) * inv * g[t] + bvec[t]);
  hrow[t + 256] = f2bf((v1 - mu) * inv * g[t + 256] + bvec[t + 256]);
  hrow[t + 512] = f2bf((v2 - mu) * inv * g[t + 512] + bvec[t + 512]);
}

// ---------------- weight transpose + bf16 convert ----------------
// dst[n][k] = src[k][n]; K=768 fixed.
__global__ __launch_bounds__(256) void transp_cvt(const float* __restrict__ Wq,
                                                  const float* __restrict__ Wk,
                                                  const float* __restrict__ Wv,
                                                  const float* __restrict__ Wo,
                                                  unsigned short* __restrict__ Bt,
                                                  unsigned short* __restrict__ Bto) {
  int z = blockIdx.z;
  const float* src; unsigned short* dst; int N;
  if (z == 0) { src = Wq; dst = Bt; N = 512; }
  else if (z == 1) { src = Wk; dst = Bt + (size_t)512 * 768; N = 512; }
  else if (z == 2) { src = Wv; dst = Bt + (size_t)1024 * 768; N = 768; }
  else { src = Wo; dst = Bto; N = 768; }
  int n0 = blockIdx.x << 6, k0 = blockIdx.y << 6;
  if (n0 >= N) return;
  __shared__ float tile[64][65];
  int t = threadIdx.x;
  int c4 = (t & 15) << 2, rr = t >> 4;
#pragma unroll
  for (int i = 0; i < 4; ++i) {
    int kr = rr + (i << 4);
    float4 v = *(const float4*)(src + (size_t)(k0 + kr) * N + n0 + c4);
    tile[c4 + 0][kr] = v.x; tile[c4 + 1][kr] = v.y;
    tile[c4 + 2][kr] = v.z; tile[c4 + 3][kr] = v.w;
  }
  __syncthreads();
  int rowN = t >> 2, kc = (t & 3) << 4;
#pragma unroll
  for (int j = 0; j < 16; ++j)
    dst[(size_t)(n0 + rowN) * 768 + k0 + kc + j] = f2bf(tile[rowN][kc + j]);
}

// ---------------- rel_k GEMM (small, fp32 in, bf16 out) ----------------
// C = A(M x K) @ B(K x N), M=4095, N=512, K=96
__global__ __launch_bounds__(256) void gemm_rel(const float* __restrict__ A,
                                                const float* __restrict__ Bw,
                                                unsigned short* __restrict__ C0,
                                                int M, int Nn, int K) {
  __shared__ float As[16][68];
  __shared__ float Bs[16][68];
  int t = threadIdx.x;
  int tx = t & 15, ty = t >> 4;
  int row0 = blockIdx.y << 6, col0 = blockIdx.x << 6;
  float acc[4][4] = {{0.f}};
  int ar = t >> 2, ac = (t & 3) << 2;
  int br = t >> 4, bc = (t & 15) << 2;
  for (int k0 = 0; k0 < K; k0 += 16) {
    float4 av = make_float4(0.f, 0.f, 0.f, 0.f);
    if (row0 + ar < M) av = *(const float4*)(A + (size_t)(row0 + ar) * K + k0 + ac);
    As[ac + 0][ar] = av.x; As[ac + 1][ar] = av.y;
    As[ac + 2][ar] = av.z; As[ac + 3][ar] = av.w;
    float4 bv = *(const float4*)(Bw + (size_t)(k0 + br) * Nn + col0 + bc);
    *(float4*)&Bs[br][bc] = bv;
    __syncthreads();
#pragma unroll
    for (int kk = 0; kk < 16; ++kk) {
      float4 a = *(const float4*)&As[kk][ty << 2];
      float4 b = *(const float4*)&Bs[kk][tx << 2];
      float arr[4] = {a.x, a.y, a.z, a.w};
      float brr[4] = {b.x, b.y, b.z, b.w};
#pragma unroll
      for (int i = 0; i < 4; ++i)
#pragma unroll
        for (int j = 0; j < 4; ++j) acc[i][j] += arr[i] * brr[j];
    }
    __syncthreads();
  }
#pragma unroll
  for (int i = 0; i < 4; ++i) {
    int r = row0 + (ty << 2) + i;
    if (r >= M) continue;
    int colb = col0 + (tx << 2);
    unsigned pk0 = f2bf(acc[i][0]) | ((unsigned)f2bf(acc[i][1]) << 16);
    unsigned pk1 = f2bf(acc[i][2]) | ((unsigned)f2bf(acc[i][3]) << 16);
    *(uint2*)(C0 + (size_t)r * Nn + colb) = make_uint2(pk0, pk1);
  }
}

// ---------------- MFMA GEMM (m97 structure): C = A(Mx768) @ Bt^T ----------------
// A bf16 row-major (K=768 contiguous), Bt bf16 N x 768 row-major.
// MODE 0: fused QKV epilogue (N=1792: q|k|v). MODE 1: out epilogue (N=768).
template <int MODE>
__global__ __launch_bounds__(256) void gemm_mfma(
    const unsigned short* __restrict__ A, const unsigned short* __restrict__ Bt,
    unsigned short* __restrict__ qw, unsigned short* __restrict__ qr,
    unsigned short* __restrict__ kbuf, unsigned short* __restrict__ vt,
    const float* __restrict__ rwb, const float* __restrict__ rrb,
    const float* __restrict__ x, const float* __restrict__ bo,
    float* __restrict__ out) {
  __shared__ __align__(16) short As[128 * 64];
  __shared__ __align__(16) short Bs[128 * 64];
  const int t = threadIdx.x;
  const int w = t >> 6, lane = t & 63;
  const int m16 = lane & 15, quad = lane >> 4;
  const int wm = w >> 1, wn = w & 1;
  const int m0 = blockIdx.y << 7, n0 = blockIdx.x << 7;
  const int K = 768;

  f4 acc[4][4];
#pragma unroll
  for (int i = 0; i < 4; ++i)
#pragma unroll
    for (int j = 0; j < 4; ++j) acc[i][j] = (f4){0.f, 0.f, 0.f, 0.f};

  const int rA = lane >> 3;   // row-within-segment
  const int cA = lane & 7;    // chunk slot

  for (int k0 = 0; k0 < K; k0 += 64) {
    __syncthreads();
#pragma unroll
    for (int i = 0; i < 4; ++i) {
      int seg = (w << 2) + i;            // 16 segments of 64 slots
      int r = (seg << 3) + rA;           // tile row 0..127
      int cg = cA ^ (r & 7);             // global chunk for this slot
      gload16(A + (size_t)(m0 + r) * K + k0 + (cg << 3), (short*)As + (seg << 9));
      gload16(Bt + (size_t)(n0 + r) * K + k0 + (cg << 3), (short*)Bs + (seg << 9));
    }
    __syncthreads();
#pragma unroll
    for (int kb = 0; kb < 2; ++kb) {
      int cs = ((kb << 2) + quad) ^ (m16 & 7);
      s8v af[4], bf[4];
#pragma unroll
      for (int mt = 0; mt < 4; ++mt) {
        int r = (wm << 6) + (mt << 4) + m16;
        af[mt] = *(const s8v*)(As + (r << 6) + (cs << 3));
      }
#pragma unroll
      for (int nt = 0; nt < 4; ++nt) {
        int rn = (wn << 6) + (nt << 4) + m16;
        bf[nt] = *(const s8v*)(Bs + (rn << 6) + (cs << 3));
      }
#pragma unroll
      for (int mt = 0; mt < 4; ++mt)
#pragma unroll
        for (int nt = 0; nt < 4; ++nt)
          acc[mt][nt] = __builtin_amdgcn_mfma_f32_16x16x32_bf16(af[mt], bf[nt], acc[mt][nt], 0, 0, 0);
    }
  }

#pragma unroll
  for (int nt = 0; nt < 4; ++nt) {
    int n = n0 + (wn << 6) + (nt << 4) + m16;
#pragma unroll
    for (int mt = 0; mt < 4; ++mt) {
#pragma unroll
      for (int rr = 0; rr < 4; ++rr) {
        int m = m0 + (wm << 6) + (mt << 4) + (quad << 2) + rr;
        float v = acc[mt][nt][rr];
        if (MODE == 0) {
          if (n < 512) {
            float vs = v * 0.125f;
            qw[(size_t)m * 512 + n] = f2bf(vs + rwb[n]);
            qr[(size_t)m * 512 + n] = f2bf(vs + rrb[n]);
          } else if (n < 1024) {
            kbuf[(size_t)m * 512 + (n - 512)] = f2bf(v);
          } else {
            int col = n - 1024;
            int b = m >> 11, j = m & 2047;
            vt[(((size_t)(b * 768 + col)) << 11) + j] = f2bf(v);
          }
        } else {
          int b = m >> 11, nn2 = m & 2047;
          int s = nn2 >> 4, rl = nn2 & 15;
          size_t base = ((size_t)((b * 128 + s) * 128 + rl)) * 768;
          out[base + n] = x[base + n] + v + bo[n];
        }
      }
    }
  }
}

// ---------------- MFMA flash attention: double-buffered gload_lds prefetch + reg-V ----------------
__global__ __launch_bounds__(256) void attn_kernel(
    const unsigned short* __restrict__ qw_g, const unsigned short* __restrict__ qr_g,
    const unsigned short* __restrict__ k_g, const unsigned short* __restrict__ vt_g,
    const unsigned short* __restrict__ rk_g, unsigned short* __restrict__ ao) {
  const int qt = blockIdx.x, hh = blockIdx.y, b = blockIdx.z;
  const int i0 = qt << 5;
  const int t = threadIdx.x;
  const int lane = t & 63, w = t >> 6;
  const int m16 = lane & 15, quad = lane >> 4;
  const int mi = w & 1, njb = w >> 1;
  const int sr = t >> 3, sg = t & 7;

  __shared__ __align__(16) short qw_s[32 * 64];
  __shared__ __align__(16) short qr_s[32 * 64];
  __shared__ __align__(16) short k_s[2][64 * 64];
  __shared__ __align__(16) short rk_s[2][96 * 64];
  __shared__ __align__(16) short pb_s[32 * 64];
  __shared__ float p_s[32][68];
  __shared__ short t_s[32][104];
  __shared__ float alpha_s[32];
  __shared__ float linv_s[32];

  // stage Q (content / rel) tiles once, XOR-swizzled for conflict-free ds_read_b128
  for (int u = t; u < 512; u += 256) {
    int tile = u >> 8, idx = u & 255, r = idx >> 3, ch = idx & 7;
    const unsigned short* src =
        (tile ? qr_g : qw_g) + (((size_t)(b * 2048 + i0 + r)) << 9) + (hh << 6) + (ch << 3);
    int4 vdat = *(const int4*)src;
    short* dst = (tile ? qr_s : qw_s) + r * 64 + (((ch ^ (r & 7))) << 3);
    *(int4*)dst = vdat;
  }

  // prologue: stage K/rel for j0=0 into buffer 0 (pre-swizzled source, linear LDS dst)
  {
    const int rb0 = 2016 - i0;  // >= 0 always
#pragma unroll
    for (int s = 0; s < 2; ++s) {
      int slot = w * 2 + s;
      int u = (slot << 6) + lane;
      int r = u >> 3, c = u & 7;
      int cg = c ^ (r & 7);
      gload16(k_g + (((size_t)(b * 2048 + r)) << 9) + (hh << 6) + (cg << 3),
              (short*)k_s[0] + (slot << 9));
    }
#pragma unroll
    for (int s = 0; s < 3; ++s) {
      int slot = w * 3 + s;
      int u = (slot << 6) + lane;
      int r = u >> 3, c = u & 7;
      int cg = c ^ (r & 7);
      int grow = rb0 + r; if (grow > 4094) grow = 4094;
      gload16(rk_g + (((size_t)grow) << 9) + (hh << 6) + (cg << 3),
              (short*)rk_s[0] + (slot << 9));
    }
  }
  __syncthreads();

  float m_i = -1e30f, l_i = 0.f;
  f4 o0 = {0.f, 0.f, 0.f, 0.f}, o1 = o0, o2 = o0;
  const int arow = mi * 16 + m16;
  const int asw = arow & 7;
  const int crow = mi * 16 + quad * 4;
  const int brow0 = njb * 16 + m16;   // njb in {0,1}
  const int bsw = brow0 & 7;

  const unsigned short* vbase = vt_g + (((size_t)(b * 768 + hh * 96 + brow0)) << 11);

  for (int j0 = 0; j0 < 2048; j0 += 64) {
    const int cur = (j0 >> 6) & 1;

    // V fragments for THIS iter into registers (consumed in PV, ~2 phases later)
    const unsigned short* vb = vbase + j0;
    s8v va0 = *(const s8v*)(vb + (quad << 3));
    s8v va1 = *(const s8v*)(vb + 65536 + (quad << 3));
    s8v va2 = *(const s8v*)(vb + 131072 + (quad << 3));
    s8v vc0 = *(const s8v*)(vb + ((4 + quad) << 3));
    s8v vc1 = *(const s8v*)(vb + 65536 + ((4 + quad) << 3));
    s8v vc2 = *(const s8v*)(vb + 131072 + ((4 + quad) << 3));

    // prefetch NEXT K/rel tile into the alternate buffer (drained at barrier A)
    if (j0 < 1984) {
      const int j0n = j0 + 64;
      const int rbn = 2016 + j0n - i0;
#pragma unroll
      for (int s = 0; s < 2; ++s) {
        int slot = w * 2 + s;
        int u = (slot << 6) + lane;
        int r = u >> 3, c = u & 7;
        int cg = c ^ (r & 7);
        gload16(k_g + (((size_t)(b * 2048 + j0n + r)) << 9) + (hh << 6) + (cg << 3),
                (short*)k_s[cur ^ 1] + (slot << 9));
      }
#pragma unroll
      for (int s = 0; s < 3; ++s) {
        int slot = w * 3 + s;
        int u = (slot << 6) + lane;
        int r = u >> 3, c = u & 7;
        int cg = c ^ (r & 7);
        int grow = rbn + r; if (grow > 4094) grow = 4094;
        gload16(rk_g + (((size_t)grow) << 9) + (hh << 6) + (cg << 3),
                (short*)rk_s[cur ^ 1] + (slot << 9));
      }
    }

    // ---- QK^T + rel from current LDS buffer ----
    const short* ks = k_s[cur];
    const short* rs = rk_s[cur];
    f4 c0 = {0.f, 0.f, 0.f, 0.f}, c1 = c0;
    f4 r0 = c0, r1 = c0, r2 = c0;
#pragma unroll
    for (int kb = 0; kb < 2; ++kb) {
      const int cidx = (kb << 2) + quad;
      const int co = (cidx ^ asw) << 3;
      const int cb = (cidx ^ bsw) << 3;
      s8v aq = *(const s8v*)(qw_s + arow * 64 + co);
      s8v ar = *(const s8v*)(qr_s + arow * 64 + co);
      s8v bk0 = *(const s8v*)(ks + brow0 * 64 + cb);
      s8v bk1 = *(const s8v*)(ks + (brow0 + 32) * 64 + cb);
      s8v br0 = *(const s8v*)(rs + brow0 * 64 + cb);
      s8v br1 = *(const s8v*)(rs + (brow0 + 32) * 64 + cb);
      s8v br2 = *(const s8v*)(rs + (brow0 + 64) * 64 + cb);
      __builtin_amdgcn_s_setprio(1);
      c0 = __builtin_amdgcn_mfma_f32_16x16x32_bf16(aq, bk0, c0, 0, 0, 0);
      c1 = __builtin_amdgcn_mfma_f32_16x16x32_bf16(aq, bk1, c1, 0, 0, 0);
      r0 = __builtin_amdgcn_mfma_f32_16x16x32_bf16(ar, br0, r0, 0, 0, 0);
      r1 = __builtin_amdgcn_mfma_f32_16x16x32_bf16(ar, br1, r1, 0, 0, 0);
      r2 = __builtin_amdgcn_mfma_f32_16x16x32_bf16(ar, br2, r2, 0, 0, 0);
      __builtin_amdgcn_s_setprio(0);
    }
#pragma unroll
    for (int rr = 0; rr < 4; ++rr) {
      p_s[crow + rr][njb * 16 + m16] = c0[rr];
      p_s[crow + rr][(njb + 2) * 16 + m16] = c1[rr];
      t_s[crow + rr][njb * 16 + m16] = (short)f2bf(r0[rr]);
      t_s[crow + rr][(njb + 2) * 16 + m16] = (short)f2bf(r1[rr]);
      t_s[crow + rr][(njb + 4) * 16 + m16] = (short)f2bf(r2[rr]);
    }
    __syncthreads();   // barrier A: publishes p_s/t_s, drains prefetch + V loads

    float sv[8];
    float mx = -1e30f;
#pragma unroll
    for (int j2 = 0; j2 < 8; ++j2) {
      int c = sg + (j2 << 3);
      float s = p_s[sr][c] + bf2f((unsigned short)t_s[sr][c - sr + 31]);
      sv[j2] = s;
      mx = fmaxf(mx, s);
    }
    mx = fmaxf(mx, __shfl_xor(mx, 1));
    mx = fmaxf(mx, __shfl_xor(mx, 2));
    mx = fmaxf(mx, __shfl_xor(mx, 4));
    float m_new = fmaxf(m_i, mx);
    float al = __expf(m_i - m_new);
    float sm = 0.f;
#pragma unroll
    for (int j2 = 0; j2 < 8; ++j2) {
      float p = __expf(sv[j2] - m_new);
      sm += p;
      pb_s[sr * 64 + ((j2 ^ (sr & 7)) << 3) + sg] = (short)f2bf(p);
    }
    sm += __shfl_xor(sm, 1);
    sm += __shfl_xor(sm, 2);
    sm += __shfl_xor(sm, 4);
    l_i = l_i * al + sm;
    m_i = m_new;
    if (sg == 0) alpha_s[sr] = al;
    __syncthreads();   // barrier B: publishes pb_s/alpha_s

#pragma unroll
    for (int rr = 0; rr < 4; ++rr) {
      float a = alpha_s[crow + rr];
      o0[rr] *= a; o1[rr] *= a; o2[rr] *= a;
    }
#pragma unroll
    for (int kb = 0; kb < 2; ++kb) {
      const int cidx = (kb << 2) + quad;
      const int co = (cidx ^ asw) << 3;
      s8v ap = *(const s8v*)(pb_s + arow * 64 + co);
      s8v b0v = kb ? vc0 : va0;
      s8v b1v = kb ? vc1 : va1;
      s8v b2v = kb ? vc2 : va2;
      __builtin_amdgcn_s_setprio(1);
      o0 = __builtin_amdgcn_mfma_f32_16x16x32_bf16(ap, b0v, o0, 0, 0, 0);
      o1 = __builtin_amdgcn_mfma_f32_16x16x32_bf16(ap, b1v, o1, 0, 0, 0);
      o2 = __builtin_amdgcn_mfma_f32_16x16x32_bf16(ap, b2v, o2, 0, 0, 0);
      __builtin_amdgcn_s_setprio(0);
    }
  }

  if (sg == 0) linv_s[sr] = 1.f / l_i;
  __syncthreads();
#pragma unroll
  for (int rr = 0; rr < 4; ++rr) {
    int row = crow + rr;
    float inv = linv_s[row];
    size_t gbase = ((size_t)(b * 2048 + i0 + row)) * 768 + hh * 96;
    ao[gbase + njb * 16 + m16] = f2bf(o0[rr] * inv);
    ao[gbase + (njb + 2) * 16 + m16] = f2bf(o1[rr] * inv);
    ao[gbase + (njb + 4) * 16 + m16] = f2bf(o2[rr] * inv);
  }
}

// ---------------- launch ----------------
extern "C" void kernel_launch(void* const* d_in, const int* in_sizes, int n_in,
                              void* d_out, int out_size, void* d_ws, size_t ws_size,
                              hipStream_t stream) {
  (void)in_sizes; (void)n_in; (void)out_size; (void)ws_size;
  const float* x = (const float*)d_in[0];
  const float* ln_g = (const float*)d_in[1];
  const float* ln_b = (const float*)d_in[2];
  const float* Wq = (const float*)d_in[3];
  const float* Wk = (const float*)d_in[4];
  const float* Wv = (const float*)d_in[5];
  const float* Wr = (const float*)d_in[6];
  const float* rwb = (const float*)d_in[7];
  const float* rrb = (const float*)d_in[8];
  const float* Wo = (const float*)d_in[9];
  const float* bo = (const float*)d_in[10];
  const float* pe = (const float*)d_in[11];
  float* out = (float*)d_out;

  char* p = (char*)d_ws;
  unsigned short* hbf = (unsigned short*)p; p += (size_t)4096 * 768 * 2;
  unsigned short* qw = (unsigned short*)p;  p += (size_t)4096 * 512 * 2;
  unsigned short* qr = (unsigned short*)p;  p += (size_t)4096 * 512 * 2;
  unsigned short* kb = (unsigned short*)p;  p += (size_t)4096 * 512 * 2;
  unsigned short* vt = (unsigned short*)p;  p += (size_t)4096 * 768 * 2;
  unsigned short* rk = (unsigned short*)p;  p += (size_t)4095 * 512 * 2;
  unsigned short* ao = (unsigned short*)p;  p += (size_t)4096 * 768 * 2;
  unsigned short* Bt = (unsigned short*)p;  p += (size_t)1792 * 768 * 2;
  unsigned short* Bto = (unsigned short*)p;

  transp_cvt<<<dim3(12, 12, 4), dim3(256), 0, stream>>>(Wq, Wk, Wv, Wo, Bt, Bto);
  copy4<<<dim3(2048), dim3(256), 0, stream>>>((const float4*)x, (float4*)out, 6291456);
  ln_kernel<<<dim3(4096), dim3(256), 0, stream>>>(x, ln_g, ln_b, hbf);
  gemm_rel<<<dim3(8, 64), dim3(256), 0, stream>>>(pe, Wr, rk, 4095, 512, 96);
  gemm_mfma<0><<<dim3(14, 32), dim3(256), 0, stream>>>(hbf, Bt, qw, qr, kb, vt, rwb, rrb,
                                                       nullptr, nullptr, nullptr);
  attn_kernel<<<dim3(64, 8, 2), dim3(256), 0, stream>>>(qw, qr, kb, vt, rk, ao);
  gemm_mfma<1><<<dim3(6, 32), dim3(256), 0, stream>>>(ao, Bto, nullptr, nullptr, nullptr,
                                                      nullptr, nullptr, nullptr, x, bo, out);
}